// Round 9
// baseline (239.400 us; speedup 1.0000x reference)
//
#include <hip/hip_runtime.h>
#include <math.h>

#define NHEAD  16
#define DHEAD  64
#define DLAT   32
#define TSEQ   2048
#define NBATCH 2
#define CDIM   1024
#define MROWS  (NBATCH*TSEQ)   // 4096

typedef __attribute__((ext_vector_type(8))) short bf16x8;
typedef __attribute__((ext_vector_type(4))) float f32x4;
typedef __attribute__((ext_vector_type(16))) float f32x16;

union frag_u { bf16x8 v; int d[4]; };

#define AS1 __attribute__((address_space(1)))
#define AS3 __attribute__((address_space(3)))

__device__ __forceinline__ unsigned short f2bf(float f) {
    union { float f; unsigned u; } v; v.f = f;
    unsigned r = v.u + 0x7fff + ((v.u >> 16) & 1);   // RNE
    return (unsigned short)(r >> 16);
}

// pack bf16(lo)|bf16(hi)<<16 by truncation — one v_perm_b32
__device__ __forceinline__ unsigned pack_trunc(float hi, float lo) {
    return __builtin_amdgcn_perm(__float_as_uint(hi), __float_as_uint(lo), 0x07060302u);
}

__device__ __forceinline__ void gld_lds16(const unsigned short* g, unsigned short* l) {
    __builtin_amdgcn_global_load_lds((const AS1 void*)g, (AS3 void*)l, 16, 0, 0);
}

// ---------------- fp32 -> bf16: x and all four weights in ONE launch ----------------
__global__ __launch_bounds__(256) void cvt_all(
        const float* __restrict__ x,  const float* __restrict__ wq,
        const float* __restrict__ wk, const float* __restrict__ wv,
        const float* __restrict__ wc,
        unsigned short* __restrict__ xb, unsigned short* __restrict__ wall) {
    int i = (blockIdx.x * 256 + threadIdx.x) * 4;
    const float* src; unsigned short* dst; int off;
    if      (i < 4194304) { src = x;  dst = xb;             off = 0;       }
    else if (i < 5242880) { src = wq; dst = wall;           off = 4194304; }
    else if (i < 5767168) { src = wk; dst = wall + 1048576; off = 5242880; }
    else if (i < 6291456) { src = wv; dst = wall + 1572864; off = 5767168; }
    else                  { src = wc; dst = wall + 2097152; off = 6291456; }
    float4 v = *(const float4*)(src + (i - off));
    ushort4 o = { f2bf(v.x), f2bf(v.y), f2bf(v.z), f2bf(v.w) };
    *(ushort4*)(dst + (i - off)) = o;
}

// ---------------- MFMA GEMM core: 128x128 tile, BK=32, 4 waves ----------------
__device__ __forceinline__ void gemm_core(
        const unsigned short* __restrict__ A, const unsigned short* __restrict__ W,
        int K, int bm, int bn, unsigned short* As, unsigned short* Bs,
        f32x4 (&acc)[4][4]) {
    const int tid = threadIdx.x;
    const int w = tid >> 6, lane = tid & 63;
    const int quad = lane >> 4, l16 = lane & 15;
    const int wm = (w >> 1) * 64, wn = (w & 1) * 64;

    const int lr = lane >> 2;
    const int le = (lane & 3) * 8;
    const unsigned short* Ag0 = A + (size_t)(bm + w*32 + lr) * K + le;
    const unsigned short* Wg0 = W + (size_t)(bn + w*32 + lr) * K + le;
    unsigned short* AsD0 = &As[(w*32 +  0) * 32];
    unsigned short* AsD1 = &As[(w*32 + 16) * 32];
    unsigned short* BsD0 = &Bs[(w*32 +  0) * 32];
    unsigned short* BsD1 = &Bs[(w*32 + 16) * 32];

    for (int k0 = 0; k0 < K; k0 += 32) {
        gld_lds16(Ag0 + k0,                AsD0);
        gld_lds16(Ag0 + k0 + (size_t)16*K, AsD1);
        gld_lds16(Wg0 + k0,                BsD0);
        gld_lds16(Wg0 + k0 + (size_t)16*K, BsD1);
        __syncthreads();
        bf16x8 af[4], bf[4];
        #pragma unroll
        for (int t = 0; t < 4; ++t)
            af[t] = *(const bf16x8*)&As[(wm + t*16 + l16)*32 + quad*8];
        #pragma unroll
        for (int c = 0; c < 4; ++c)
            bf[c] = *(const bf16x8*)&Bs[(wn + c*16 + l16)*32 + quad*8];
        #pragma unroll
        for (int t = 0; t < 4; ++t)
            #pragma unroll
            for (int c = 0; c < 4; ++c)
                acc[t][c] = __builtin_amdgcn_mfma_f32_16x16x32_bf16(af[t], bf[c], acc[t][c], 0, 0, 0);
        __syncthreads();
    }
}

__global__ __launch_bounds__(256) void gemm_proj(
        const unsigned short* __restrict__ A, const unsigned short* __restrict__ W,
        float* __restrict__ qproj, float* __restrict__ okl, float* __restrict__ ovl,
        int K) {
    __shared__ unsigned short As[128*32];
    __shared__ unsigned short Bs[128*32];
    const int bm = blockIdx.y * 128, bn = blockIdx.x * 128;
    f32x4 acc[4][4] = {};
    gemm_core(A, W, K, bm, bn, As, Bs, acc);

    const int tid = threadIdx.x;
    const int w = tid >> 6, lane = tid & 63;
    const int quad = lane >> 4, l16 = lane & 15;
    const int wm = (w >> 1) * 64, wn = (w & 1) * 64;

    float* base; int ldo;
    if (bn < 1024)      { base = qproj + bn;        ldo = 1024; }
    else if (bn < 1536) { base = okl + (bn - 1024); ldo = 512;  }
    else                { base = ovl + (bn - 1536); ldo = 512;  }

    #pragma unroll
    for (int t = 0; t < 4; ++t)
        #pragma unroll
        for (int c = 0; c < 4; ++c)
            #pragma unroll
            for (int r = 0; r < 4; ++r) {
                int row = bm + wm + t*16 + quad*4 + r;
                int col = wn + c*16 + l16;
                base[(size_t)row * ldo + col] = acc[t][c][r];
            }
}

__global__ __launch_bounds__(256) void gemm_out(
        const unsigned short* __restrict__ A, const unsigned short* __restrict__ W,
        float* __restrict__ O, int N, int K) {
    __shared__ unsigned short As[128*32];
    __shared__ unsigned short Bs[128*32];
    const int bm = blockIdx.y * 128, bn = blockIdx.x * 128;
    f32x4 acc[4][4] = {};
    gemm_core(A, W, K, bm, bn, As, Bs, acc);

    const int tid = threadIdx.x;
    const int w = tid >> 6, lane = tid & 63;
    const int quad = lane >> 4, l16 = lane & 15;
    const int wm = (w >> 1) * 64, wn = (w & 1) * 64;
    #pragma unroll
    for (int t = 0; t < 4; ++t)
        #pragma unroll
        for (int c = 0; c < 4; ++c)
            #pragma unroll
            for (int r = 0; r < 4; ++r) {
                int row = bm + wm + t*16 + quad*4 + r;
                int col = bn + wn + c*16 + l16;
                O[(size_t)row * N + col] = acc[t][c][r];
            }
}

// ---------------- fused latent up-proj (k,v) + q load + RoPE ----------------
// q is pre-scaled by 1/sqrt(64) * log2(e) so flash softmax can use raw exp2.
__global__ __launch_bounds__(256) void latup(
        const float* __restrict__ qproj, const float* __restrict__ klat,
        const float* __restrict__ vlat,  const float* __restrict__ Wku,
        const float* __restrict__ Wvu,
        unsigned short* __restrict__ qb, unsigned short* __restrict__ kb,
        unsigned short* __restrict__ vt) {
    __shared__ float kls[64][36];
    __shared__ float vls[64][36];
    __shared__ unsigned short vts[64][72];
    const int bh = blockIdx.y, b = bh >> 4, h = bh & 15;
    const int t0 = blockIdx.x * 64;
    const int tid = threadIdx.x;
    {
        const int r = tid >> 2, cs = (tid & 3) * 8;
        const float* ksrc = klat + ((size_t)(b*TSEQ + t0 + r))*(NHEAD*DLAT) + h*DLAT + cs;
        const float* vsrc = vlat + ((size_t)(b*TSEQ + t0 + r))*(NHEAD*DLAT) + h*DLAT + cs;
        *(float4*)&kls[r][cs]   = *(const float4*)ksrc;
        *(float4*)&kls[r][cs+4] = *(const float4*)(ksrc + 4);
        *(float4*)&vls[r][cs]   = *(const float4*)vsrc;
        *(float4*)&vls[r][cs+4] = *(const float4*)(vsrc + 4);
    }
    __syncthreads();
    const int tl = tid & 63;
    const int dg = tid >> 6;
    const int t = t0 + tl;

    float ca[16], sa[16];
    #pragma unroll
    for (int i = 0; i < 16; ++i) {
        int d = dg*16 + i;
        float inv = __expf(-(float)(d & 31) * 0.28782313662425572f);
        __sincosf((float)t * inv, &sa[i], &ca[i]);
    }
    float kl_r[DLAT], vl_r[DLAT];
    #pragma unroll
    for (int l = 0; l < DLAT; ++l) { kl_r[l] = kls[tl][l]; vl_r[l] = vls[tl][l]; }

    float kv[16], vv[16], qv[16];
    #pragma unroll
    for (int i = 0; i < 16; ++i) {
        int d = dg*16 + i;
        float a0 = 0.f, a1 = 0.f;
        #pragma unroll
        for (int l = 0; l < DLAT; ++l) {
            a0 += kl_r[l] * Wku[d*DLAT + l];
            a1 += vl_r[l] * Wvu[d*DLAT + l];
        }
        kv[i] = a0; vv[i] = a1;
    }
    {
        const float* qsrc = qproj + ((size_t)(b*TSEQ + t))*CDIM + h*DHEAD + dg*16;
        #pragma unroll
        for (int i = 0; i < 4; ++i) {
            float4 v4 = *(const float4*)(qsrc + i*4);
            qv[i*4+0]=v4.x; qv[i*4+1]=v4.y; qv[i*4+2]=v4.z; qv[i*4+3]=v4.w;
        }
    }
    const float QS = 0.18033688011112042f;   // 0.125 * log2(e)
    unsigned kw[8], qw[8];
    #pragma unroll
    for (int i = 0; i < 8; ++i) {
        int e = 2*i, o = e + 1;
        float ke = kv[e]*ca[e] - kv[o]*sa[e];
        float ko = kv[o]*ca[o] + kv[e]*sa[o];
        float qe = (qv[e]*ca[e] - qv[o]*sa[e]) * QS;
        float qo = (qv[o]*ca[o] + qv[e]*sa[o]) * QS;
        kw[i] = (unsigned)f2bf(ke) | ((unsigned)f2bf(ko) << 16);
        qw[i] = (unsigned)f2bf(qe) | ((unsigned)f2bf(qo) << 16);
    }
    size_t orow = ((size_t)bh*TSEQ + t)*DHEAD + dg*16;
    *(int4*)&kb[orow]     = make_int4(kw[0], kw[1], kw[2], kw[3]);
    *(int4*)&kb[orow + 8] = make_int4(kw[4], kw[5], kw[6], kw[7]);
    *(int4*)&qb[orow]     = make_int4(qw[0], qw[1], qw[2], qw[3]);
    *(int4*)&qb[orow + 8] = make_int4(qw[4], qw[5], qw[6], qw[7]);

    #pragma unroll
    for (int i = 0; i < 16; ++i) vts[dg*16 + i][tl] = f2bf(vv[i]);
    __syncthreads();
    const int r2 = tid >> 2, c2 = (tid & 3) * 16;
    int4 w0 = *(const int4*)&vts[r2][c2];
    int4 w1 = *(const int4*)&vts[r2][c2 + 8];
    unsigned short* vdst = vt + ((size_t)bh*DHEAD + r2)*TSEQ + t0 + c2;
    *(int4*)&vdst[0] = w0;
    *(int4*)&vdst[8] = w1;
}

// ---------------- Flash attention: 32x32x16 MFMA, 32 q-rows/wave ----------------
// Block = 128 q-rows (4 waves x 32), K-tile = 128, DMA staging + XOR swizzle (R7).
// 32x32 C-layout: col=lane&31 (q-row), row=(reg&3)+8*(reg>>2)+4*(lane>>5) (k-col).
// Per-lane softmax stats; lane pair (l, l^32) shares a q-row -> 1-step shfl reduce.
// P^T B-frags: pack_trunc + shfl_xor(32) half-exchange (no bpermute, no LDS trip).
// Grid (32 bh, 16), qtile = 15-y, longest first: in-order dispatch self-balances
// to exactly 17 tile-iters per CU (16+1, 15+2, ...).
__global__ __launch_bounds__(256, 2) void flash_attn(
        const unsigned short* __restrict__ qb, const unsigned short* __restrict__ kb,
        const unsigned short* __restrict__ vtb, unsigned short* __restrict__ yatt) {
    const int bh = blockIdx.x;
    const int b = bh >> 4, h = bh & 15;
    const int qt = 15 - (int)blockIdx.y;          // 128-row q-tile
    const int n128 = qt + 1;

    __shared__ unsigned short Ks[2][128][64];     // 32 KB (t, d)
    __shared__ unsigned short VTs[2][64][128];    // 32 KB (d, t)

    const int tid  = threadIdx.x;
    const int wq   = tid >> 6;
    const int lane = tid & 63;
    const int hl   = lane >> 5;                   // half of wave
    const int l31  = lane & 31;
    const int l15  = lane & 15;

    const unsigned short* Kbase = kb  + (size_t)bh * TSEQ * DHEAD;
    const unsigned short* Vbase = vtb + (size_t)bh * DHEAD * TSEQ;

    // DMA staging lane-mapping (identical to R7)
    const int kr8 = lane >> 3, kcp = lane & 7;
    const int kcl = (kcp ^ kr8) * 8;
    const int vr4 = lane >> 4, vcp = lane & 15;

    // Q B-frags: lane holds Q[qrow][d = 16*ki + 8*hl + j]
    const int qrow_g = qt*128 + wq*32 + l31;
    const unsigned short* qp = qb + ((size_t)bh*TSEQ + qrow_g) * DHEAD;
    bf16x8 qB[4];
    #pragma unroll
    for (int ki = 0; ki < 4; ++ki)
        qB[ki] = *(const bf16x8*)(qp + (2*ki + hl)*8);

    f32x16 oacc[2] = {};                          // O^T chunks: d = c*32+rho, col=q
    float m_run = -1e30f, l_run = 0.f;

    // preload tile 0
    #pragma unroll
    for (int i = 0; i < 4; ++i) {
        gld_lds16(Kbase + (size_t)(wq*32 + i*8 + kr8)*DHEAD + kcl,
                  &Ks[0][wq*32 + i*8][0]);
        int vcl = (vcp ^ ((i*4 + vr4) & 15)) * 8;
        gld_lds16(Vbase + (size_t)(wq*16 + i*4 + vr4)*TSEQ + vcl,
                  &VTs[0][wq*16 + i*4][0]);
    }
    __syncthreads();

    for (int j = 0; j < n128; ++j) {
        const int buf = j & 1;
        if (j + 1 < n128) {   // async DMA prefetch into buf^1
            const int kc = (j + 1) * 128;
            #pragma unroll
            for (int i = 0; i < 4; ++i) {
                gld_lds16(Kbase + (size_t)(kc + wq*32 + i*8 + kr8)*DHEAD + kcl,
                          &Ks[buf^1][wq*32 + i*8][0]);
                int vcl = (vcp ^ ((i*4 + vr4) & 15)) * 8;
                gld_lds16(Vbase + (size_t)(wq*16 + i*4 + vr4)*TSEQ + kc + vcl,
                          &VTs[buf^1][wq*16 + i*4][0]);
            }
        }

        // S^T = K Q^T : 4 chunks of 32 k-rows, each 4 MFMAs over d
        f32x16 sacc[4];
        #pragma unroll
        for (int c = 0; c < 4; ++c) {
            f32x16 z = {};
            #pragma unroll
            for (int ki = 0; ki < 4; ++ki) {
                bf16x8 ak = *(const bf16x8*)&Ks[buf][c*32 + l31][(((2*ki + hl) ^ (l31 & 7))) * 8];
                z = __builtin_amdgcn_mfma_f32_32x32x16_bf16(ak, qB[ki], z, 0, 0, 0);
            }
            sacc[c] = z;
        }
        if (j == n128 - 1) {   // causal mask: kcol_local > qrow_local
            #pragma unroll
            for (int c = 0; c < 4; ++c)
                #pragma unroll
                for (int r = 0; r < 16; ++r) {
                    int rho = (r & 3) + 8*(r >> 2) + 4*hl;
                    if (c*32 + rho > wq*32 + l31) sacc[c][r] = -1e30f;
                }
        }

        // online softmax (log2 domain; q pre-scaled by log2e/8)
        float mx = -1e30f;
        #pragma unroll
        for (int c = 0; c < 4; ++c)
            #pragma unroll
            for (int r = 0; r < 16; ++r) mx = fmaxf(mx, sacc[c][r]);
        mx = fmaxf(mx, __shfl_xor(mx, 32, 64));
        float mn = fmaxf(m_run, mx);
        float alpha = exp2f(m_run - mn);
        m_run = mn;

        float ls = 0.f;
        frag_u bP[8];                              // B-frags for PV, indexed by ti
        #pragma unroll
        for (int c = 0; c < 4; ++c) {
            float p[16];
            #pragma unroll
            for (int r = 0; r < 16; ++r) {
                p[r] = exp2f(sacc[c][r] - mn);
                ls += p[r];
            }
            #pragma unroll
            for (int kp = 0; kp < 2; ++kp) {      // kp: rho 0-15 / 16-31
                unsigned pA = pack_trunc(p[8*kp+1], p[8*kp+0]);
                unsigned pB = pack_trunc(p[8*kp+3], p[8*kp+2]);
                unsigned pC = pack_trunc(p[8*kp+5], p[8*kp+4]);
                unsigned pD = pack_trunc(p[8*kp+7], p[8*kp+6]);
                int xA = __shfl_xor((int)pA, 32, 64);
                int xB = __shfl_xor((int)pB, 32, 64);
                int xC = __shfl_xor((int)pC, 32, 64);
                int xD = __shfl_xor((int)pD, 32, 64);
                frag_u f;
                f.d[0] = hl ? xC : (int)pA;
                f.d[1] = hl ? xD : (int)pB;
                f.d[2] = hl ? (int)pC : xA;
                f.d[3] = hl ? (int)pD : xB;
                bP[c*2 + kp] = f;
            }
        }
        ls += __shfl_xor(ls, 32, 64);
        l_run = l_run * alpha + ls;
        #pragma unroll
        for (int c = 0; c < 2; ++c)
            #pragma unroll
            for (int r = 0; r < 16; ++r) oacc[c][r] *= alpha;

        // O^T += V^T P^T : 2 d-chunks x 8 t-instrs
        #pragma unroll
        for (int c = 0; c < 2; ++c)
            #pragma unroll
            for (int ti = 0; ti < 8; ++ti) {
                bf16x8 av = *(const bf16x8*)&VTs[buf][c*32 + l31][(((2*ti + hl) ^ l15)) * 8];
                oacc[c] = __builtin_amdgcn_mfma_f32_32x32x16_bf16(av, bP[ti].v, oacc[c], 0, 0, 0);
            }

        __syncthreads();   // drains prefetch DMA + protects buf swap
    }

    // epilogue: O^T -> O via per-wave LDS scratch, coalesced 16B stores
    float invl = 1.0f / l_run;
    unsigned short* Wt = &Ks[0][0][0] + wq * (32*72);
    #pragma unroll
    for (int c = 0; c < 2; ++c)
        #pragma unroll
        for (int r = 0; r < 16; ++r) {
            int rho = (r & 3) + 8*(r >> 2) + 4*hl;
            Wt[(size_t)l31*72 + c*32 + rho] = f2bf(oacc[c][r] * invl);
        }
    __asm__ __volatile__("" ::: "memory");   // same-wave DS ordering
    #pragma unroll
    for (int p = 0; p < 4; ++p) {
        int row = p*8 + (lane >> 3);
        int d0 = (lane & 7) * 8;
        int4 val = *(const int4*)&Wt[row*72 + d0];
        int tg = qt*128 + wq*32 + row;
        *(int4*)&yatt[((size_t)(b*TSEQ + tg))*CDIM + h*DHEAD + d0] = val;
    }
}

extern "C" void kernel_launch(void* const* d_in, const int* in_sizes, int n_in,
                              void* d_out, int out_size, void* d_ws, size_t ws_size,
                              hipStream_t stream) {
    const float* x   = (const float*)d_in[0];
    const float* Wq  = (const float*)d_in[1];
    const float* Wk  = (const float*)d_in[2];
    const float* Wv  = (const float*)d_in[3];
    const float* Wku = (const float*)d_in[4];
    const float* Wvu = (const float*)d_in[5];
    const float* Wc  = (const float*)d_in[6];

    float* out_y  = (float*)d_out;
    float* out_kl = out_y  + (size_t)MROWS * CDIM;
    float* out_vl = out_kl + (size_t)MROWS * NHEAD*DLAT;

    float* qproj = (float*)d_ws;                                           // 16 MB fp32
    unsigned short* xb   = (unsigned short*)(qproj + (size_t)MROWS*CDIM);  // 8 MB
    unsigned short* qb   = xb  + (size_t)MROWS*CDIM;                       // 8 MB
    unsigned short* kb   = qb  + (size_t)MROWS*CDIM;                       // 8 MB
    unsigned short* vt   = kb  + (size_t)MROWS*CDIM;                       // 8 MB
    unsigned short* wall = vt  + (size_t)MROWS*CDIM;                       // [Wq;Wk;Wv;Wc] 6 MB
    unsigned short* wcb  = wall + (size_t)2048*CDIM;
    unsigned short* yatt = (unsigned short*)qproj;   // alias: qproj dead after latup

    cvt_all<<<(4194304 + 3145728)/1024, 256, 0, stream>>>(x, Wq, Wk, Wv, Wc, xb, wall);

    gemm_proj<<<dim3(2048/128, MROWS/128), 256, 0, stream>>>(
        xb, wall, qproj, out_kl, out_vl, CDIM);

    latup<<<dim3(TSEQ/64, NBATCH*NHEAD), 256, 0, stream>>>(
        qproj, out_kl, out_vl, Wku, Wvu, qb, kb, vt);

    flash_attn<<<dim3(NBATCH*NHEAD, 16), 256, 0, stream>>>(qb, kb, vt, yatt);

    gemm_out<<<dim3(CDIM/128, MROWS/128), 256, 0, stream>>>(yatt, wcb, out_y, CDIM, CDIM);
}